// Round 1
// baseline (144.115 us; speedup 1.0000x reference)
//
#include <hip/hip_runtime.h>

#define N_L 8

// ---------------------------------------------------------------------------
// Softmax row loader: reproduces reference scatter semantics.
//   full[fixed_indices[j]] = fixed_params[j]
//   full[sorted complement] = trainable_params (in order)
// => row for vertex v: binary-search v in sorted fixed_indices; if found at j,
//    use fixed[j], else trainable[v - (#fixed < v)].
// ---------------------------------------------------------------------------
__device__ __forceinline__ void load_P_row(int v,
                                           const float* __restrict__ tr,
                                           const float* __restrict__ fx,
                                           const int* __restrict__ fidx,
                                           int nF, float p[N_L]) {
  int lo = 0, hi = nF;
  while (lo < hi) {
    int mid = (lo + hi) >> 1;
    if (fidx[mid] < v) lo = mid + 1; else hi = mid;
  }
  const float* src = (lo < nF && fidx[lo] == v)
                         ? (fx + (size_t)lo * N_L)
                         : (tr + (size_t)(v - lo) * N_L);
  float4 a = *(const float4*)src;
  float4 b = *(const float4*)(src + 4);
  p[0] = a.x; p[1] = a.y; p[2] = a.z; p[3] = a.w;
  p[4] = b.x; p[5] = b.y; p[6] = b.z; p[7] = b.w;
  float m = p[0];
#pragma unroll
  for (int i = 1; i < N_L; ++i) m = fmaxf(m, p[i]);
  float s = 0.f;
#pragma unroll
  for (int i = 0; i < N_L; ++i) { p[i] = __expf(p[i] - m); s += p[i]; }
  float r = 1.0f / s;
#pragma unroll
  for (int i = 0; i < N_L; ++i) p[i] *= r;
}

// Block (256 threads = 4 waves) sum reduction; result valid on thread 0.
__device__ __forceinline__ float block_reduce_sum(float v, float* smem) {
#pragma unroll
  for (int off = 32; off > 0; off >>= 1) v += __shfl_down(v, off, 64);
  int lane = threadIdx.x & 63;
  int wid  = threadIdx.x >> 6;
  if (lane == 0) smem[wid] = v;
  __syncthreads();
  if (threadIdx.x < 4) {
    v = smem[threadIdx.x];
    v += __shfl_down(v, 2, 64);
    v += __shfl_down(v, 1, 64);
  }
  return v;
}

__global__ void init_acc(double* acc) { acc[0] = 0.0; }

// Pair contribution to out: per pair, -(p.q)   [constant 2*nP added at finalize]
__global__ __launch_bounds__(256) void pair_kernel(
    const int* __restrict__ simp, int n,
    const float* __restrict__ tr, const float* __restrict__ fx,
    const int* __restrict__ fidx, int nF, double* __restrict__ acc) {
  __shared__ float smem[4];
  int i = blockIdx.x * blockDim.x + threadIdx.x;
  float local = 0.f;
  if (i < n) {
    int2 vv = ((const int2*)simp)[i];
    float p[N_L], q[N_L];
    load_P_row(vv.x, tr, fx, fidx, nF, p);
    load_P_row(vv.y, tr, fx, fidx, nF, q);
    float d = 0.f;
#pragma unroll
    for (int t = 0; t < N_L; ++t) d += p[t] * q[t];
    local = -d;
  }
  float bsum = block_reduce_sum(local, smem);
  if (threadIdx.x == 0) atomicAdd(acc, (double)bsum);
}

// Triple contribution: -4*(p.q + p.r + q.r) + (16/3)*sum_i p_i q_i r_i
// [constant 8*nT added at finalize]
__global__ __launch_bounds__(256) void triple_kernel(
    const int* __restrict__ simp, int n,
    const float* __restrict__ tr, const float* __restrict__ fx,
    const int* __restrict__ fidx, int nF, double* __restrict__ acc) {
  __shared__ float smem[4];
  int i = blockIdx.x * blockDim.x + threadIdx.x;
  float local = 0.f;
  if (i < n) {
    int v0 = simp[3 * i + 0];
    int v1 = simp[3 * i + 1];
    int v2 = simp[3 * i + 2];
    float p[N_L], q[N_L], r[N_L];
    load_P_row(v0, tr, fx, fidx, nF, p);
    load_P_row(v1, tr, fx, fidx, nF, q);
    load_P_row(v2, tr, fx, fidx, nF, r);
    float d01 = 0.f, d02 = 0.f, d12 = 0.f, t3 = 0.f;
#pragma unroll
    for (int t = 0; t < N_L; ++t) {
      d01 += p[t] * q[t];
      d02 += p[t] * r[t];
      d12 += q[t] * r[t];
      t3  += p[t] * q[t] * r[t];
    }
    local = -4.0f * (d01 + d02 + d12) + (16.0f / 3.0f) * t3;
  }
  float bsum = block_reduce_sum(local, smem);
  if (threadIdx.x == 0) atomicAdd(acc, (double)bsum);
}

__global__ void finalize(const double* __restrict__ acc,
                         float* __restrict__ out, double cst) {
  out[0] = (float)(cst + acc[0]);
}

extern "C" void kernel_launch(void* const* d_in, const int* in_sizes, int n_in,
                              void* d_out, int out_size, void* d_ws, size_t ws_size,
                              hipStream_t stream) {
  const float* tr   = (const float*)d_in[0];  // (N_V-N_FIXED, 8) f32
  const float* fx   = (const float*)d_in[1];  // (N_FIXED, 8) f32
  const int*   fidx = (const int*)d_in[2];    // (N_FIXED,) i32 (sorted)
  const int*   s1   = (const int*)d_in[3];    // (nP, 2) i32
  const int*   s2   = (const int*)d_in[4];    // (nT, 3) i32

  int nF = in_sizes[2];
  int nP = in_sizes[3] / 2;
  int nT = in_sizes[4] / 3;

  double* acc = (double*)d_ws;   // 8 bytes of scratch
  float*  out = (float*)d_out;

  init_acc<<<1, 1, 0, stream>>>(acc);
  pair_kernel<<<(nP + 255) / 256, 256, 0, stream>>>(s1, nP, tr, fx, fidx, nF, acc);
  triple_kernel<<<(nT + 255) / 256, 256, 0, stream>>>(s2, nT, tr, fx, fidx, nF, acc);

  // out = 2*clique1 + 4*clique2
  //     = 2*nP - sum(p.q) + 8*nT + sum(-4*(d01+d02+d12) + (16/3)*T)
  double cst = 2.0 * (double)nP + 8.0 * (double)nT;
  finalize<<<1, 1, 0, stream>>>(acc, out, cst);
}

// Round 2
// 134.458 us; speedup vs baseline: 1.0718x; 1.0718x over previous
//
#include <hip/hip_runtime.h>

#define N_L 8

// ---------------------------------------------------------------------------
// Scatter semantics (reference): full[fixed_indices] = fixed_params;
// full[sorted complement] = trainable_params in order. For vertex v:
// binary-search v in sorted fidx; found at j -> fixed[j], else trainable[v-j].
// ---------------------------------------------------------------------------
__device__ __forceinline__ const float* resolve_row(int v,
                                                    const float* __restrict__ tr,
                                                    const float* __restrict__ fx,
                                                    const int* __restrict__ fidx,
                                                    int nF) {
  int lo = 0, hi = nF;
  while (lo < hi) {
    int mid = (lo + hi) >> 1;
    if (fidx[mid] < v) lo = mid + 1; else hi = mid;
  }
  return (lo < nF && fidx[lo] == v) ? (fx + (size_t)lo * N_L)
                                    : (tr + (size_t)(v - lo) * N_L);
}

__device__ __forceinline__ void softmax8(const float* __restrict__ src, float p[N_L]) {
  float4 a = *(const float4*)src;
  float4 b = *(const float4*)(src + 4);
  p[0] = a.x; p[1] = a.y; p[2] = a.z; p[3] = a.w;
  p[4] = b.x; p[5] = b.y; p[6] = b.z; p[7] = b.w;
  float m = p[0];
#pragma unroll
  for (int i = 1; i < N_L; ++i) m = fmaxf(m, p[i]);
  float s = 0.f;
#pragma unroll
  for (int i = 0; i < N_L; ++i) { p[i] = __expf(p[i] - m); s += p[i]; }
  float r = 1.0f / s;
#pragma unroll
  for (int i = 0; i < N_L; ++i) p[i] *= r;
}

// Block (256 threads = 4 waves) sum reduction; result valid on thread 0.
__device__ __forceinline__ float block_reduce_sum(float v, float* smem) {
#pragma unroll
  for (int off = 32; off > 0; off >>= 1) v += __shfl_down(v, off, 64);
  int lane = threadIdx.x & 63;
  int wid  = threadIdx.x >> 6;
  if (lane == 0) smem[wid] = v;
  __syncthreads();
  if (threadIdx.x < 4) {
    v = smem[threadIdx.x];
    v += __shfl_down(v, 2, 64);
    v += __shfl_down(v, 1, 64);
  }
  return v;
}

// ---------------------------------------------------------------------------
// Path A: materialize softmax table P (nV x 8) into workspace, then gather.
// ---------------------------------------------------------------------------
__global__ __launch_bounds__(256) void materialize_P(
    const float* __restrict__ tr, const float* __restrict__ fx,
    const int* __restrict__ fidx, int nF, int nV,
    float* __restrict__ P, double* __restrict__ acc) {
  int v = blockIdx.x * 256 + threadIdx.x;
  if (v == 0) acc[0] = 0.0;
  if (v >= nV) return;
  const float* src = resolve_row(v, tr, fx, fidx, nF);
  float p[N_L];
  softmax8(src, p);
  float4* dst = (float4*)(P + (size_t)v * N_L);
  dst[0] = make_float4(p[0], p[1], p[2], p[3]);
  dst[1] = make_float4(p[4], p[5], p[6], p[7]);
}

// Fused pair+triple gather. Blocks [0, pairBlocks) -> pairs, rest -> triples.
// Pair term per pair:   -(p.q)                        [+2 per pair at finalize]
// Triple term per tri:  -4*(d01+d02+d12) + (16/3)*T   [+8 per tri at finalize]
__global__ __launch_bounds__(256) void gather_energy(
    const int* __restrict__ s1, int nP,
    const int* __restrict__ s2, int nT,
    const float* __restrict__ P, double* __restrict__ acc, int pairBlocks) {
  __shared__ float smem[4];
  float local = 0.f;
  if ((int)blockIdx.x < pairBlocks) {
    int i = blockIdx.x * 256 + threadIdx.x;
    if (i < nP) {
      int2 vv = ((const int2*)s1)[i];
      const float4* A = (const float4*)(P + (size_t)vv.x * N_L);
      const float4* B = (const float4*)(P + (size_t)vv.y * N_L);
      float4 a0 = A[0], a1 = A[1], b0 = B[0], b1 = B[1];
      float d = a0.x * b0.x + a0.y * b0.y + a0.z * b0.z + a0.w * b0.w
              + a1.x * b1.x + a1.y * b1.y + a1.z * b1.z + a1.w * b1.w;
      local = -d;
    }
  } else {
    int i = (blockIdx.x - pairBlocks) * 256 + threadIdx.x;
    if (i < nT) {
      int v0 = s2[3 * i + 0];
      int v1 = s2[3 * i + 1];
      int v2 = s2[3 * i + 2];
      const float4* A = (const float4*)(P + (size_t)v0 * N_L);
      const float4* B = (const float4*)(P + (size_t)v1 * N_L);
      const float4* C = (const float4*)(P + (size_t)v2 * N_L);
      float4 a0 = A[0], a1 = A[1];
      float4 b0 = B[0], b1 = B[1];
      float4 c0 = C[0], c1 = C[1];
      float pa[8] = {a0.x, a0.y, a0.z, a0.w, a1.x, a1.y, a1.z, a1.w};
      float pb[8] = {b0.x, b0.y, b0.z, b0.w, b1.x, b1.y, b1.z, b1.w};
      float pc[8] = {c0.x, c0.y, c0.z, c0.w, c1.x, c1.y, c1.z, c1.w};
      float d01 = 0.f, d02 = 0.f, d12 = 0.f, t3 = 0.f;
#pragma unroll
      for (int t = 0; t < N_L; ++t) {
        d01 += pa[t] * pb[t];
        d02 += pa[t] * pc[t];
        d12 += pb[t] * pc[t];
        t3  += pa[t] * pb[t] * pc[t];
      }
      local = -4.0f * (d01 + d02 + d12) + (16.0f / 3.0f) * t3;
    }
  }
  float bsum = block_reduce_sum(local, smem);
  if (threadIdx.x == 0) atomicAdd(acc, (double)bsum);
}

// ---------------------------------------------------------------------------
// Path B (fallback, ws too small): fully fused per-simplex softmax (round 0).
// ---------------------------------------------------------------------------
__global__ void init_acc(double* acc) { acc[0] = 0.0; }

__device__ __forceinline__ void load_P_row_fused(int v,
                                                 const float* __restrict__ tr,
                                                 const float* __restrict__ fx,
                                                 const int* __restrict__ fidx,
                                                 int nF, float p[N_L]) {
  softmax8(resolve_row(v, tr, fx, fidx, nF), p);
}

__global__ __launch_bounds__(256) void pair_kernel_fused(
    const int* __restrict__ simp, int n,
    const float* __restrict__ tr, const float* __restrict__ fx,
    const int* __restrict__ fidx, int nF, double* __restrict__ acc) {
  __shared__ float smem[4];
  int i = blockIdx.x * blockDim.x + threadIdx.x;
  float local = 0.f;
  if (i < n) {
    int2 vv = ((const int2*)simp)[i];
    float p[N_L], q[N_L];
    load_P_row_fused(vv.x, tr, fx, fidx, nF, p);
    load_P_row_fused(vv.y, tr, fx, fidx, nF, q);
    float d = 0.f;
#pragma unroll
    for (int t = 0; t < N_L; ++t) d += p[t] * q[t];
    local = -d;
  }
  float bsum = block_reduce_sum(local, smem);
  if (threadIdx.x == 0) atomicAdd(acc, (double)bsum);
}

__global__ __launch_bounds__(256) void triple_kernel_fused(
    const int* __restrict__ simp, int n,
    const float* __restrict__ tr, const float* __restrict__ fx,
    const int* __restrict__ fidx, int nF, double* __restrict__ acc) {
  __shared__ float smem[4];
  int i = blockIdx.x * blockDim.x + threadIdx.x;
  float local = 0.f;
  if (i < n) {
    int v0 = simp[3 * i + 0];
    int v1 = simp[3 * i + 1];
    int v2 = simp[3 * i + 2];
    float p[N_L], q[N_L], r[N_L];
    load_P_row_fused(v0, tr, fx, fidx, nF, p);
    load_P_row_fused(v1, tr, fx, fidx, nF, q);
    load_P_row_fused(v2, tr, fx, fidx, nF, r);
    float d01 = 0.f, d02 = 0.f, d12 = 0.f, t3 = 0.f;
#pragma unroll
    for (int t = 0; t < N_L; ++t) {
      d01 += p[t] * q[t];
      d02 += p[t] * r[t];
      d12 += q[t] * r[t];
      t3  += p[t] * q[t] * r[t];
    }
    local = -4.0f * (d01 + d02 + d12) + (16.0f / 3.0f) * t3;
  }
  float bsum = block_reduce_sum(local, smem);
  if (threadIdx.x == 0) atomicAdd(acc, (double)bsum);
}

__global__ void finalize(const double* __restrict__ acc,
                         float* __restrict__ out, double cst) {
  out[0] = (float)(cst + acc[0]);
}

extern "C" void kernel_launch(void* const* d_in, const int* in_sizes, int n_in,
                              void* d_out, int out_size, void* d_ws, size_t ws_size,
                              hipStream_t stream) {
  const float* tr   = (const float*)d_in[0];  // (N_V-N_FIXED, 8) f32
  const float* fx   = (const float*)d_in[1];  // (N_FIXED, 8) f32
  const int*   fidx = (const int*)d_in[2];    // (N_FIXED,) i32 (sorted)
  const int*   s1   = (const int*)d_in[3];    // (nP, 2) i32
  const int*   s2   = (const int*)d_in[4];    // (nT, 3) i32

  int nF = in_sizes[2];
  int nP = in_sizes[3] / 2;
  int nT = in_sizes[4] / 3;
  int nV = (in_sizes[0] + in_sizes[1]) / N_L;

  double* acc = (double*)d_ws;                  // 8 B
  float*  P   = (float*)((char*)d_ws + 256);    // nV*8 f32, 32B-aligned rows
  float*  out = (float*)d_out;

  size_t need = 256 + (size_t)nV * N_L * sizeof(float);
  double cst = 2.0 * (double)nP + 8.0 * (double)nT;

  if (ws_size >= need) {
    int mBlocks = (nV + 255) / 256;
    materialize_P<<<mBlocks, 256, 0, stream>>>(tr, fx, fidx, nF, nV, P, acc);
    int pairBlocks = (nP + 255) / 256;
    int triBlocks  = (nT + 255) / 256;
    gather_energy<<<pairBlocks + triBlocks, 256, 0, stream>>>(
        s1, nP, s2, nT, P, acc, pairBlocks);
  } else {
    init_acc<<<1, 1, 0, stream>>>(acc);
    pair_kernel_fused<<<(nP + 255) / 256, 256, 0, stream>>>(s1, nP, tr, fx, fidx, nF, acc);
    triple_kernel_fused<<<(nT + 255) / 256, 256, 0, stream>>>(s2, nT, tr, fx, fidx, nF, acc);
  }
  finalize<<<1, 1, 0, stream>>>(acc, out, cst);
}